// Round 1
// baseline (4653.997 us; speedup 1.0000x reference)
//
#include <hip/hip_runtime.h>
#include <math.h>

#define B 16
#define CIN 512
#define COUT 512
#define KS 3
#define SDIM 512
#define H 64
#define W 64

// runtime-equalized scales from the reference
__device__ __constant__ float LIN_SCALE  = 0.04419417382415922f;   // 1/sqrt(512)
__device__ __constant__ float CONV_SCALE = 0.014731391274719742f;  // 1/sqrt(512*9)

// ---------------------------------------------------------------------------
// Kernel 1: s[b,ci] = style[b,:] . style_w[ci,:] * lin_scale + style_b[ci]
// also emits s2 = s*s for the demod reduction.
// grid = B, block = 512 (thread = ci)
// ---------------------------------------------------------------------------
__global__ __launch_bounds__(512) void style_mod_kernel(
    const float* __restrict__ style, const float* __restrict__ style_w,
    const float* __restrict__ style_b, float* __restrict__ s,
    float* __restrict__ s2) {
  const int b = blockIdx.x;
  const int ci = threadIdx.x;
  __shared__ float st[SDIM];
  st[ci] = style[b * SDIM + ci];
  __syncthreads();

  const float4* wr = reinterpret_cast<const float4*>(style_w + (size_t)ci * SDIM);
  float acc = 0.f;
#pragma unroll 4
  for (int k = 0; k < SDIM / 4; ++k) {
    float4 wv = wr[k];
    acc += st[4 * k + 0] * wv.x + st[4 * k + 1] * wv.y +
           st[4 * k + 2] * wv.z + st[4 * k + 3] * wv.w;
  }
  float v = acc * LIN_SCALE + style_b[ci];
  s[b * CIN + ci] = v;
  s2[b * CIN + ci] = v * v;
}

// ---------------------------------------------------------------------------
// Kernel 2: wsq[co,ci] = sum_k weight[co,ci,k]^2
// ---------------------------------------------------------------------------
__global__ __launch_bounds__(256) void wsq_kernel(
    const float* __restrict__ weight, float* __restrict__ wsq) {
  const int i = blockIdx.x * blockDim.x + threadIdx.x;
  if (i >= COUT * CIN) return;
  const float* p = weight + (size_t)i * 9;
  float a = 0.f;
#pragma unroll
  for (int k = 0; k < 9; ++k) {
    float v = p[k];
    a += v * v;
  }
  wsq[i] = a;
}

// ---------------------------------------------------------------------------
// Kernel 3: outscale[b,co] = conv_scale * rsqrt(conv_scale^2 * sum_ci s2*wsq + 1e-8)
// grid = B, block = 512 (thread = co)
// ---------------------------------------------------------------------------
__global__ __launch_bounds__(512) void dcoef_kernel(
    const float* __restrict__ s2, const float* __restrict__ wsq,
    float* __restrict__ outscale) {
  const int b = blockIdx.x;
  const int co = threadIdx.x;
  __shared__ float sh[CIN];
  sh[co] = s2[b * CIN + co];
  __syncthreads();

  const float4* wr = reinterpret_cast<const float4*>(wsq + (size_t)co * CIN);
  float acc = 0.f;
#pragma unroll 4
  for (int k = 0; k < CIN / 4; ++k) {
    float4 wv = wr[k];
    acc += sh[4 * k + 0] * wv.x + sh[4 * k + 1] * wv.y +
           sh[4 * k + 2] * wv.z + sh[4 * k + 3] * wv.w;
  }
  float d = rsqrtf(acc * CONV_SCALE * CONV_SCALE + 1e-8f);
  outscale[b * COUT + co] = d * CONV_SCALE;
}

// ---------------------------------------------------------------------------
// Kernel 4: the grouped conv.
// Tile per 256-thread block: 32 co x 4 h x 64 w. ci chunked by 8, staged in LDS.
// Thread (w8 = tid&7, h4 = (tid>>3)&3, cog = tid>>5) computes acc[4 co][8 w]
// at output row h0+h4, cols w8*8..w8*8+7, cos co0+cog*4..+3.
// s[b,ci] is folded into the staged weight tile; dcoef*conv_scale in epilogue.
// ---------------------------------------------------------------------------
#define COB 32
#define HB 4
#define CB 8
#define XW 68  // padded LDS row width (floats); 68*4 = 272 B = 16B-multiple

__global__ __launch_bounds__(256) void conv_kernel(
    const float* __restrict__ x, const float* __restrict__ weight,
    const float* __restrict__ s, const float* __restrict__ outscale,
    float* __restrict__ out) {
  __shared__ float xs[CB][HB + 2][XW];  // 8*6*68*4 = 13056 B
  __shared__ float ws[CB][9][COB];      // 8*9*32*4 =  9216 B

  const int tid = threadIdx.x;
  const int hb = blockIdx.x;  // 0..15
  const int cb = blockIdx.y;  // 0..15
  const int b = blockIdx.z;   // 0..15

  const int w8 = tid & 7;
  const int h4 = (tid >> 3) & 3;
  const int cog = tid >> 5;  // 0..7

  const int h0 = hb * HB;
  const int co0 = cb * COB;

  float acc[4][8];
#pragma unroll
  for (int c = 0; c < 4; ++c)
#pragma unroll
    for (int w = 0; w < 8; ++w) acc[c][w] = 0.f;

  for (int c0 = 0; c0 < CIN; c0 += CB) {
    // ---- stage x tile: CB ci x (HB+2) rows x 66 cols (zero-padded halo)
    for (int e = tid; e < CB * (HB + 2) * 66; e += 256) {
      int ci = e / ((HB + 2) * 66);
      int rem = e - ci * ((HB + 2) * 66);
      int r = rem / 66;
      int col = rem - r * 66;
      int gr = h0 - 1 + r;
      int gc = col - 1;
      float v = 0.f;
      if ((unsigned)gr < H && (unsigned)gc < W)
        v = x[(((size_t)b * CIN + c0 + ci) * H + gr) * W + gc];
      xs[ci][r][col] = v;
    }
    // ---- stage w tile (s folded in): 2304 elements, 9 exact passes
    for (int e = tid; e < CB * COB * 9; e += 256) {
      int p = e / 9;       // p = co*CB + ci  -> contiguous 72-float global runs
      int k9 = e - p * 9;
      int ci = p & (CB - 1);
      int co = p >> 3;
      float sv = s[b * CIN + c0 + ci];
      ws[ci][k9][co] =
          weight[((size_t)(co0 + co) * CIN + c0 + ci) * 9 + k9] * sv;
    }
    __syncthreads();

    // ---- compute
    for (int ci = 0; ci < CB; ++ci) {
#pragma unroll
      for (int kh = 0; kh < 3; ++kh) {
        const float* xrow = &xs[ci][h4 + kh][w8 * 8];
        float4 xa = *reinterpret_cast<const float4*>(xrow);
        float4 xb = *reinterpret_cast<const float4*>(xrow + 4);
        float4 xc = *reinterpret_cast<const float4*>(xrow + 8);
        float xr[12] = {xa.x, xa.y, xa.z, xa.w, xb.x, xb.y,
                        xb.z, xb.w, xc.x, xc.y, xc.z, xc.w};
#pragma unroll
        for (int kw = 0; kw < 3; ++kw) {
          float4 wv =
              *reinterpret_cast<const float4*>(&ws[ci][kh * 3 + kw][cog * 4]);
          float wa[4] = {wv.x, wv.y, wv.z, wv.w};
#pragma unroll
          for (int c = 0; c < 4; ++c)
#pragma unroll
            for (int w = 0; w < 8; ++w)
              acc[c][w] = fmaf(wa[c], xr[w + kw], acc[c][w]);
        }
      }
    }
    __syncthreads();
  }

  // ---- epilogue: scale by dcoef*conv_scale, store
  const int hrow = h0 + h4;
#pragma unroll
  for (int c = 0; c < 4; ++c) {
    const int gco = co0 + cog * 4 + c;
    const float osc = outscale[b * COUT + gco];
    float4 o0 = make_float4(acc[c][0] * osc, acc[c][1] * osc, acc[c][2] * osc,
                            acc[c][3] * osc);
    float4 o1 = make_float4(acc[c][4] * osc, acc[c][5] * osc, acc[c][6] * osc,
                            acc[c][7] * osc);
    float4* dst = reinterpret_cast<float4*>(
        &out[(((size_t)b * COUT + gco) * H + hrow) * W + w8 * 8]);
    dst[0] = o0;
    dst[1] = o1;
  }
}

// ---------------------------------------------------------------------------
extern "C" void kernel_launch(void* const* d_in, const int* in_sizes, int n_in,
                              void* d_out, int out_size, void* d_ws,
                              size_t ws_size, hipStream_t stream) {
  const float* x = (const float*)d_in[0];
  const float* style = (const float*)d_in[1];
  const float* weight = (const float*)d_in[2];
  const float* style_w = (const float*)d_in[3];
  const float* style_b = (const float*)d_in[4];
  float* out = (float*)d_out;

  // workspace layout (floats): s[8192] | s2[8192] | wsq[262144] | outscale[8192]
  float* wsp = (float*)d_ws;
  float* s = wsp;
  float* s2 = wsp + B * CIN;
  float* wsq = wsp + 2 * B * CIN;
  float* outscale = wsp + 2 * B * CIN + COUT * CIN;

  style_mod_kernel<<<B, 512, 0, stream>>>(style, style_w, style_b, s, s2);
  wsq_kernel<<<(COUT * CIN + 255) / 256, 256, 0, stream>>>(weight, wsq);
  dcoef_kernel<<<B, 512, 0, stream>>>(s2, wsq, outscale);

  dim3 grid(H / HB, COUT / COB, B);
  conv_kernel<<<grid, 256, 0, stream>>>(x, weight, s, outscale, out);
}

// Round 2
// 559.092 us; speedup vs baseline: 8.3242x; 8.3242x over previous
//
#include <hip/hip_runtime.h>
#include <math.h>

#define B 16
#define CIN 512
#define COUT 512
#define KS 3
#define SDIM 512
#define H 64
#define W 64

typedef short s16x8 __attribute__((ext_vector_type(8)));
typedef float f32x4 __attribute__((ext_vector_type(4)));

// runtime-equalized scales from the reference
__device__ __constant__ float LIN_SCALE  = 0.04419417382415922f;   // 1/sqrt(512)
__device__ __constant__ float CONV_SCALE = 0.014731391274719742f;  // 1/sqrt(512*9)

__device__ __forceinline__ ushort f2bf(float f) {
  unsigned u = __float_as_uint(f);
  return (ushort)((u + 0x7FFFu + ((u >> 16) & 1u)) >> 16);  // RNE
}

// ---------------------------------------------------------------------------
// Kernel 1: s[b,ci] = style[b,:] . style_w[ci,:] * lin_scale + style_b[ci]
// ---------------------------------------------------------------------------
__global__ __launch_bounds__(512) void style_mod_kernel(
    const float* __restrict__ style, const float* __restrict__ style_w,
    const float* __restrict__ style_b, float* __restrict__ s,
    float* __restrict__ s2) {
  const int b = blockIdx.x;
  const int ci = threadIdx.x;
  __shared__ float st[SDIM];
  st[ci] = style[b * SDIM + ci];
  __syncthreads();

  const float4* wr = reinterpret_cast<const float4*>(style_w + (size_t)ci * SDIM);
  float acc = 0.f;
#pragma unroll 4
  for (int k = 0; k < SDIM / 4; ++k) {
    float4 wv = wr[k];
    acc += st[4 * k + 0] * wv.x + st[4 * k + 1] * wv.y +
           st[4 * k + 2] * wv.z + st[4 * k + 3] * wv.w;
  }
  float v = acc * LIN_SCALE + style_b[ci];
  s[b * CIN + ci] = v;
  s2[b * CIN + ci] = v * v;
}

// ---------------------------------------------------------------------------
// Kernel 2: wsq[co,ci] = sum_k weight[co,ci,k]^2
// ---------------------------------------------------------------------------
__global__ __launch_bounds__(256) void wsq_kernel(
    const float* __restrict__ weight, float* __restrict__ wsq) {
  const int i = blockIdx.x * blockDim.x + threadIdx.x;
  if (i >= COUT * CIN) return;
  const float* p = weight + (size_t)i * 9;
  float a = 0.f;
#pragma unroll
  for (int k = 0; k < 9; ++k) {
    float v = p[k];
    a += v * v;
  }
  wsq[i] = a;
}

// ---------------------------------------------------------------------------
// Kernel 3: outscale[b,co] = conv_scale * rsqrt(conv_scale^2 * sum + 1e-8)
// ---------------------------------------------------------------------------
__global__ __launch_bounds__(512) void dcoef_kernel(
    const float* __restrict__ s2, const float* __restrict__ wsq,
    float* __restrict__ outscale) {
  const int b = blockIdx.x;
  const int co = threadIdx.x;
  __shared__ float sh[CIN];
  sh[co] = s2[b * CIN + co];
  __syncthreads();

  const float4* wr = reinterpret_cast<const float4*>(wsq + (size_t)co * CIN);
  float acc = 0.f;
#pragma unroll 4
  for (int k = 0; k < CIN / 4; ++k) {
    float4 wv = wr[k];
    acc += sh[4 * k + 0] * wv.x + sh[4 * k + 1] * wv.y +
           sh[4 * k + 2] * wv.z + sh[4 * k + 3] * wv.w;
  }
  float d = rsqrtf(acc * CONV_SCALE * CONV_SCALE + 1e-8f);
  outscale[b * COUT + co] = d * CONV_SCALE;
}

// ---------------------------------------------------------------------------
// Kernel 4: MFMA implicit-GEMM grouped conv.
// Block: 256 thr (4 waves). Tile: 64 co x (4 rows x 64 cols). Wave wid owns
// row h0+wid, all 64 cols, all 64 co -> 4x4 mfma_f32_16x16x32_bf16 frags.
// K = ci(512, chunks of 32) x 9 taps. LDS ci-innermost bf16 layouts:
//   xs[6 rows][66 cols][32 ci]   (halo'd x tile, zero-padded)
//   ws[9 j][64 co][32 ci]        (s[b,ci] folded in)
// A-frag:  lane reads ws[j][mt*16 + (lane&15)][(lane>>4)*8 ..+8]  (b128,
//          64 lanes = contiguous 1KB, conflict-free)
// B-frag:  lane reads xs[wid+kh][nt*16 + (lane&15) + kw][(lane>>4)*8 ..+8]
// D: col(pixel)=lane&15, row(co)=(lane>>4)*4+reg  [m89-verified layout]
// ---------------------------------------------------------------------------
__global__ __launch_bounds__(256, 2) void conv_mfma_kernel(
    const float* __restrict__ x, const float* __restrict__ weight,
    const float* __restrict__ s, const float* __restrict__ outscale,
    float* __restrict__ out) {
  __shared__ ushort xs[6][66][32];  // 25344 B
  __shared__ ushort ws[9][64][32];  // 36864 B

  const int tid = threadIdx.x;
  const int hb = blockIdx.x;   // 0..15
  const int cb = blockIdx.y;   // 0..7
  const int b  = blockIdx.z;   // 0..15
  const int h0 = hb * 4;
  const int co0 = cb * 64;
  const int lane = tid & 63;
  const int wid = tid >> 6;          // wave id 0..3 -> output row h0+wid
  const int l15 = lane & 15;
  const int l4  = lane >> 4;         // 0..3

  f32x4 acc[4][4];
#pragma unroll
  for (int mt = 0; mt < 4; ++mt)
#pragma unroll
    for (int nt = 0; nt < 4; ++nt) acc[mt][nt] = (f32x4)0.f;

  // ws staging: exactly one item per thread: (co = tid>>2, ci-octet = tid&3)
  const int wq = tid & 3;
  const int wco = tid >> 2;

  for (int c0 = 0; c0 < CIN; c0 += 32) {
    // ---- stage ws: thread loads weight[co0+wco][c0+wq*8 .. +7][0..8]
    // = 72 contiguous floats (288B) as 18 float4 (16B-aligned), all used.
    {
      const float4* wp = reinterpret_cast<const float4*>(
          weight + ((size_t)(co0 + wco) * CIN + c0 + wq * 8) * 9);
      float wv[72];
#pragma unroll
      for (int t = 0; t < 18; ++t) {
        float4 v = wp[t];
        wv[4 * t + 0] = v.x; wv[4 * t + 1] = v.y;
        wv[4 * t + 2] = v.z; wv[4 * t + 3] = v.w;
      }
      float sv[8];
#pragma unroll
      for (int i = 0; i < 8; ++i) sv[i] = s[b * CIN + c0 + wq * 8 + i];
#pragma unroll
      for (int j = 0; j < 9; ++j) {
        s16x8 p;
#pragma unroll
        for (int i = 0; i < 8; ++i)
          p[i] = (short)f2bf(wv[i * 9 + j] * sv[i]);
        *reinterpret_cast<s16x8*>(&ws[j][wco][wq * 8]) = p;
      }
    }
    // ---- stage xs: items (r 0..5, cc 0..65, q 0..3) = 1584, q fastest so
    // consecutive threads write contiguous LDS (conflict-free b128 writes).
#pragma unroll
    for (int it = 0; it < 7; ++it) {
      int e = tid + it * 256;
      if (e < 6 * 66 * 4) {
        int q = e & 3;
        int t2 = e >> 2;
        int cc = t2 % 66;
        int r = t2 / 66;
        int gr = h0 - 1 + r;
        int gc = cc - 1;
        s16x8 p;
        if ((unsigned)gr < H && (unsigned)gc < W) {
          const float* xp =
              x + (((size_t)b * CIN + c0 + q * 8) * H + gr) * W + gc;
#pragma unroll
          for (int i = 0; i < 8; ++i) p[i] = (short)f2bf(xp[(size_t)i * H * W]);
        } else {
#pragma unroll
          for (int i = 0; i < 8; ++i) p[i] = 0;
        }
        *reinterpret_cast<s16x8*>(&xs[r][cc][q * 8]) = p;
      }
    }
    __syncthreads();

    // ---- compute: 9 taps x (4 A-frags + 4 B-frags + 16 mfma)
#pragma unroll
    for (int kh = 0; kh < 3; ++kh) {
#pragma unroll
      for (int kw = 0; kw < 3; ++kw) {
        const int j = kh * 3 + kw;
        s16x8 af[4], bf[4];
#pragma unroll
        for (int mt = 0; mt < 4; ++mt)
          af[mt] = *reinterpret_cast<const s16x8*>(
              &ws[j][mt * 16 + l15][l4 * 8]);
#pragma unroll
        for (int nt = 0; nt < 4; ++nt)
          bf[nt] = *reinterpret_cast<const s16x8*>(
              &xs[wid + kh][nt * 16 + l15 + kw][l4 * 8]);
#pragma unroll
        for (int mt = 0; mt < 4; ++mt)
#pragma unroll
          for (int nt = 0; nt < 4; ++nt)
            acc[mt][nt] = __builtin_amdgcn_mfma_f32_16x16x32_bf16(
                af[mt], bf[nt], acc[mt][nt], 0, 0, 0);
      }
    }
    __syncthreads();
  }

  // ---- epilogue: D col=pixel (lane&15), row=co ((lane>>4)*4+reg)
  const int h = h0 + wid;
#pragma unroll
  for (int mt = 0; mt < 4; ++mt) {
#pragma unroll
    for (int r = 0; r < 4; ++r) {
      const int co = co0 + mt * 16 + l4 * 4 + r;
      const float osc = outscale[b * COUT + co];
      float* orow = out + (((size_t)b * COUT + co) * H + h) * W;
#pragma unroll
      for (int nt = 0; nt < 4; ++nt)
        orow[nt * 16 + l15] = acc[mt][nt][r] * osc;
    }
  }
}

// ---------------------------------------------------------------------------
extern "C" void kernel_launch(void* const* d_in, const int* in_sizes, int n_in,
                              void* d_out, int out_size, void* d_ws,
                              size_t ws_size, hipStream_t stream) {
  const float* x = (const float*)d_in[0];
  const float* style = (const float*)d_in[1];
  const float* weight = (const float*)d_in[2];
  const float* style_w = (const float*)d_in[3];
  const float* style_b = (const float*)d_in[4];
  float* out = (float*)d_out;

  // workspace layout (floats): s[8192] | s2[8192] | wsq[262144] | outscale[8192]
  float* wsp = (float*)d_ws;
  float* s = wsp;
  float* s2 = wsp + B * CIN;
  float* wsq = wsp + 2 * B * CIN;
  float* outscale = wsp + 2 * B * CIN + COUT * CIN;

  style_mod_kernel<<<B, 512, 0, stream>>>(style, style_w, style_b, s, s2);
  wsq_kernel<<<(COUT * CIN + 255) / 256, 256, 0, stream>>>(weight, wsq);
  dcoef_kernel<<<B, 512, 0, stream>>>(s2, wsq, outscale);

  dim3 grid(H / 4, COUT / 64, B);
  conv_mfma_kernel<<<grid, 256, 0, stream>>>(x, weight, s, outscale, out);
}

// Round 3
// 343.685 us; speedup vs baseline: 13.5414x; 1.6268x over previous
//
#include <hip/hip_runtime.h>
#include <math.h>

#define B 16
#define CIN 512
#define COUT 512
#define SDIM 512
#define H 64
#define W 64

typedef short s16x8 __attribute__((ext_vector_type(8)));
typedef float f32x4 __attribute__((ext_vector_type(4)));

__device__ __constant__ float LIN_SCALE  = 0.04419417382415922f;   // 1/sqrt(512)
__device__ __constant__ float CONV_SCALE = 0.014731391274719742f;  // 1/sqrt(512*9)

__device__ __forceinline__ ushort f2bf(float f) {
  unsigned u = __float_as_uint(f);
  return (ushort)((u + 0x7FFFu + ((u >> 16) & 1u)) >> 16);  // RNE
}

#define GLOAD16(g, l)                                           \
  __builtin_amdgcn_global_load_lds(                             \
      (const __attribute__((address_space(1))) unsigned*)(g),   \
      (__attribute__((address_space(3))) unsigned*)(l), 16, 0, 0)

// ---------------------------------------------------------------------------
// Kernel 1: s[b,ci] = style[b,:] . style_w[ci,:] * lin_scale + style_b[ci]
// ---------------------------------------------------------------------------
__global__ __launch_bounds__(512) void style_mod_kernel(
    const float* __restrict__ style, const float* __restrict__ style_w,
    const float* __restrict__ style_b, float* __restrict__ s,
    float* __restrict__ s2) {
  const int b = blockIdx.x;
  const int ci = threadIdx.x;
  __shared__ float st[SDIM];
  st[ci] = style[b * SDIM + ci];
  __syncthreads();

  const float4* wr = reinterpret_cast<const float4*>(style_w + (size_t)ci * SDIM);
  float acc = 0.f;
#pragma unroll 4
  for (int k = 0; k < SDIM / 4; ++k) {
    float4 wv = wr[k];
    acc += st[4 * k + 0] * wv.x + st[4 * k + 1] * wv.y +
           st[4 * k + 2] * wv.z + st[4 * k + 3] * wv.w;
  }
  float v = acc * LIN_SCALE + style_b[ci];
  s[b * CIN + ci] = v;
  s2[b * CIN + ci] = v * v;
}

// ---------------------------------------------------------------------------
// Kernel 2: wsq[co,ci] = sum_k weight[co,ci,k]^2
// ---------------------------------------------------------------------------
__global__ __launch_bounds__(256) void wsq_kernel(
    const float* __restrict__ weight, float* __restrict__ wsq) {
  const int i = blockIdx.x * blockDim.x + threadIdx.x;
  if (i >= COUT * CIN) return;
  const float* p = weight + (size_t)i * 9;
  float a = 0.f;
#pragma unroll
  for (int k = 0; k < 9; ++k) {
    float v = p[k];
    a += v * v;
  }
  wsq[i] = a;
}

// ---------------------------------------------------------------------------
// Kernel 3: outscale[b,co] = conv_scale * rsqrt(conv_scale^2 * sum + 1e-8)
// ---------------------------------------------------------------------------
__global__ __launch_bounds__(512) void dcoef_kernel(
    const float* __restrict__ s2, const float* __restrict__ wsq,
    float* __restrict__ outscale) {
  const int b = blockIdx.x;
  const int co = threadIdx.x;
  __shared__ float sh[CIN];
  sh[co] = s2[b * CIN + co];
  __syncthreads();

  const float4* wr = reinterpret_cast<const float4*>(wsq + (size_t)co * CIN);
  float acc = 0.f;
#pragma unroll 4
  for (int k = 0; k < CIN / 4; ++k) {
    float4 wv = wr[k];
    acc += sh[4 * k + 0] * wv.x + sh[4 * k + 1] * wv.y +
           sh[4 * k + 2] * wv.z + sh[4 * k + 3] * wv.w;
  }
  float d = rsqrtf(acc * CONV_SCALE * CONV_SCALE + 1e-8f);
  outscale[b * COUT + co] = d * CONV_SCALE;
}

// ---------------------------------------------------------------------------
// Kernel P1: pack weights -> wt[chunk][j][co][slot][8ci] bf16, where the
// ci-octet slot is stored permuted: slot = s ^ ((co>>1)&3). This bakes the
// LDS bank swizzle into the global layout so conv can global_load_lds
// linearly and ds_read with the matching XOR (2-way max = free).
// Byte strides: chunk 294912, j 32768, co 64, slot 16.
// ---------------------------------------------------------------------------
__global__ __launch_bounds__(256) void pack_w_kernel(
    const float* __restrict__ w, ushort* __restrict__ wt) {
  const int t = blockIdx.x * 256 + threadIdx.x;  // 32768 threads
  const int s = t & 3;
  const int chunk = (t >> 2) & 15;
  const int co = t >> 6;
  const float4* wp =
      (const float4*)(w + ((size_t)co * 512 + chunk * 32 + s * 8) * 9);
  float wv[72];
#pragma unroll
  for (int i = 0; i < 18; ++i) {
    float4 v = wp[i];
    wv[4 * i + 0] = v.x; wv[4 * i + 1] = v.y;
    wv[4 * i + 2] = v.z; wv[4 * i + 3] = v.w;
  }
  const int sp = s ^ ((co >> 1) & 3);
  ushort* dst = wt + (size_t)chunk * 147456 + (size_t)co * 32 + sp * 8;
#pragma unroll
  for (int j = 0; j < 9; ++j) {
    s16x8 p;
#pragma unroll
    for (int i = 0; i < 8; ++i) p[i] = (short)f2bf(wv[i * 9 + j]);
    *(s16x8*)(dst + (size_t)j * 16384) = p;
  }
}

// ---------------------------------------------------------------------------
// Kernel P2: pack x -> xp[b][chunk][gr][c][slot][8ci] bf16 with s[b,ci]
// folded in; slot = s ^ (((c+1)>>1)&3)  (c+1 = LDS col after halo shift).
// Byte strides: (b,chunk) 262144, gr 4096, c 64, slot 16.
// ---------------------------------------------------------------------------
__global__ __launch_bounds__(256) void pack_x_kernel(
    const float* __restrict__ x, const float* __restrict__ smod,
    ushort* __restrict__ xp) {
  __shared__ float xt[32][65];
  __shared__ float sm[32];
  const int tid = threadIdx.x;
  const int gr = blockIdx.x, chunk = blockIdx.y, b = blockIdx.z;
  if (tid < 32) sm[tid] = smod[b * 512 + chunk * 32 + tid];
  {
    const int ci = tid >> 3, cq = tid & 7;
    const float4* rp = (const float4*)(
        x + (((size_t)b * 512 + chunk * 32 + ci) * 64 + gr) * 64 + cq * 8);
    float4 a = rp[0], c2 = rp[1];
    float* row = &xt[ci][cq * 8];
    row[0] = a.x; row[1] = a.y; row[2] = a.z; row[3] = a.w;
    row[4] = c2.x; row[5] = c2.y; row[6] = c2.z; row[7] = c2.w;
  }
  __syncthreads();
  const int c = tid >> 2, s = tid & 3;
  s16x8 p;
#pragma unroll
  for (int i = 0; i < 8; ++i)
    p[i] = (short)f2bf(xt[s * 8 + i][c] * sm[s * 8 + i]);
  const int sp = s ^ (((c + 1) >> 1) & 3);
  *(s16x8*)(xp + ((size_t)(b * 16 + chunk) * 64 + gr) * 2048 + c * 32 + sp * 8) = p;
}

// ---------------------------------------------------------------------------
// Kernel 4 (new): MFMA implicit-GEMM conv from packed operands.
// Block 256 thr / 4 waves; tile 64co x (4h x 64w); wave wid owns row h0+wid.
// Per ci-chunk(32): stage ws[9][64][32] + xs[6][66][32] via global_load_lds
// width-16 (15 instrs/wave), then 9 taps x (8 swizzled ds_read_b128 +
// 16 mfma_f32_16x16x32_bf16). Halo cols 0/65 + OOB rows stay pre-zeroed.
// ---------------------------------------------------------------------------
__global__ __launch_bounds__(256, 2) void conv_mfma2_kernel(
    const ushort* __restrict__ wt, const ushort* __restrict__ xp,
    const float* __restrict__ outscale, float* __restrict__ out) {
  __shared__ ushort ws[9][64][32];  // 36864 B
  __shared__ ushort xs[6][66][32];  // 25344 B (row stride 4224 B)

  const int tid = threadIdx.x;
  const int hb = blockIdx.x, cb = blockIdx.y, b = blockIdx.z;
  const int h0 = hb * 4, co0 = cb * 64;
  const int lane = tid & 63, wid = tid >> 6;
  const int l15 = lane & 15, l4 = lane >> 4;

  // zero xs once: covers halo cols 0/65 and OOB edge rows for all chunks
  {
    s16x8* p = (s16x8*)&xs[0][0][0];
    for (int e = tid; e < 1584; e += 256) p[e] = (s16x8)0;
  }

  f32x4 acc[4][4];
#pragma unroll
  for (int mt = 0; mt < 4; ++mt)
#pragma unroll
    for (int nt = 0; nt < 4; ++nt) acc[mt][nt] = (f32x4)0.f;

  // precomputed swizzled lane offsets (loop-invariant)
  const int am = (l4 ^ ((l15 >> 1) & 3)) * 16;
  int aoff[4];
#pragma unroll
  for (int mt = 0; mt < 4; ++mt) aoff[mt] = (mt * 16 + l15) * 64 + am;
  int boff[12];
#pragma unroll
  for (int nt = 0; nt < 4; ++nt)
#pragma unroll
    for (int kw = 0; kw < 3; ++kw) {
      int col = nt * 16 + l15 + kw;
      boff[nt * 3 + kw] =
          wid * 4224 + col * 64 + ((l4 ^ ((col >> 1) & 3)) * 16);
    }

  const char* wsrc0 = (const char*)wt + cb * 4096 + wid * 1024 + lane * 16;
  const char* xsrc0 =
      (const char*)xp + (size_t)b * 4194304 + wid * 1024 + lane * 16;
  char* wdst = (char*)&ws[0][0][0] + wid * 1024 + lane * 16;
  char* xdst = (char*)&xs[0][0][0] + 64 + wid * 1024 + lane * 16;

  __syncthreads();

  for (int chunk = 0; chunk < 16; ++chunk) {
    const char* wsrc = wsrc0 + chunk * 294912;
    const char* xsrc = xsrc0 + chunk * 262144;
#pragma unroll
    for (int t = 0; t < 9; ++t)
      GLOAD16(wsrc + t * 32768, wdst + t * 4096);
#pragma unroll
    for (int t = 0; t < 6; ++t) {
      int gr = h0 - 1 + t;
      if ((unsigned)gr < 64u) GLOAD16(xsrc + gr * 4096, xdst + t * 4224);
    }
    __syncthreads();  // drains vmcnt -> staged data visible

#pragma unroll
    for (int kh = 0; kh < 3; ++kh) {
      const char* xrow = (const char*)&xs[0][0][0] + kh * 4224;
#pragma unroll
      for (int kw = 0; kw < 3; ++kw) {
        const int j = kh * 3 + kw;
        const char* wj = (const char*)&ws[0][0][0] + j * 4096;
        s16x8 af[4], bf[4];
#pragma unroll
        for (int mt = 0; mt < 4; ++mt)
          af[mt] = *(const s16x8*)(wj + aoff[mt]);
#pragma unroll
        for (int nt = 0; nt < 4; ++nt)
          bf[nt] = *(const s16x8*)(xrow + boff[nt * 3 + kw]);
#pragma unroll
        for (int mt = 0; mt < 4; ++mt)
#pragma unroll
          for (int nt = 0; nt < 4; ++nt)
            acc[mt][nt] = __builtin_amdgcn_mfma_f32_16x16x32_bf16(
                af[mt], bf[nt], acc[mt][nt], 0, 0, 0);
      }
    }
    __syncthreads();  // protect LDS before next chunk's staging
  }

  // epilogue: D col(pixel)=lane&15, row(co)=(lane>>4)*4+reg
  const int h = h0 + wid;
#pragma unroll
  for (int mt = 0; mt < 4; ++mt) {
#pragma unroll
    for (int r = 0; r < 4; ++r) {
      const int co = co0 + mt * 16 + l4 * 4 + r;
      const float osc = outscale[b * COUT + co];
      float* orow = out + (((size_t)b * COUT + co) * H + h) * W;
#pragma unroll
      for (int nt = 0; nt < 4; ++nt)
        orow[nt * 16 + l15] = acc[mt][nt][r] * osc;
    }
  }
}

// ---------------------------------------------------------------------------
// Fallback conv (R2): used if ws_size can't hold the packed operands.
// ---------------------------------------------------------------------------
__global__ __launch_bounds__(256, 2) void conv_mfma_kernel(
    const float* __restrict__ x, const float* __restrict__ weight,
    const float* __restrict__ s, const float* __restrict__ outscale,
    float* __restrict__ out) {
  __shared__ ushort xs[6][66][32];
  __shared__ ushort ws[9][64][32];

  const int tid = threadIdx.x;
  const int hb = blockIdx.x;
  const int cb = blockIdx.y;
  const int b  = blockIdx.z;
  const int h0 = hb * 4;
  const int co0 = cb * 64;
  const int lane = tid & 63;
  const int wid = tid >> 6;
  const int l15 = lane & 15;
  const int l4  = lane >> 4;

  f32x4 acc[4][4];
#pragma unroll
  for (int mt = 0; mt < 4; ++mt)
#pragma unroll
    for (int nt = 0; nt < 4; ++nt) acc[mt][nt] = (f32x4)0.f;

  const int wq = tid & 3;
  const int wco = tid >> 2;

  for (int c0 = 0; c0 < CIN; c0 += 32) {
    {
      const float4* wp = reinterpret_cast<const float4*>(
          weight + ((size_t)(co0 + wco) * CIN + c0 + wq * 8) * 9);
      float wv[72];
#pragma unroll
      for (int t = 0; t < 18; ++t) {
        float4 v = wp[t];
        wv[4 * t + 0] = v.x; wv[4 * t + 1] = v.y;
        wv[4 * t + 2] = v.z; wv[4 * t + 3] = v.w;
      }
      float sv[8];
#pragma unroll
      for (int i = 0; i < 8; ++i) sv[i] = s[b * CIN + c0 + wq * 8 + i];
#pragma unroll
      for (int j = 0; j < 9; ++j) {
        s16x8 p;
#pragma unroll
        for (int i = 0; i < 8; ++i)
          p[i] = (short)f2bf(wv[i * 9 + j] * sv[i]);
        *reinterpret_cast<s16x8*>(&ws[j][wco][wq * 8]) = p;
      }
    }
#pragma unroll
    for (int it = 0; it < 7; ++it) {
      int e = tid + it * 256;
      if (e < 6 * 66 * 4) {
        int q = e & 3;
        int t2 = e >> 2;
        int cc = t2 % 66;
        int r = t2 / 66;
        int gr = h0 - 1 + r;
        int gc = cc - 1;
        s16x8 p;
        if ((unsigned)gr < H && (unsigned)gc < W) {
          const float* xp2 =
              x + (((size_t)b * CIN + c0 + q * 8) * H + gr) * W + gc;
#pragma unroll
          for (int i = 0; i < 8; ++i) p[i] = (short)f2bf(xp2[(size_t)i * H * W]);
        } else {
#pragma unroll
          for (int i = 0; i < 8; ++i) p[i] = 0;
        }
        *reinterpret_cast<s16x8*>(&xs[r][cc][q * 8]) = p;
      }
    }
    __syncthreads();

#pragma unroll
    for (int kh = 0; kh < 3; ++kh) {
#pragma unroll
      for (int kw = 0; kw < 3; ++kw) {
        const int j = kh * 3 + kw;
        s16x8 af[4], bf[4];
#pragma unroll
        for (int mt = 0; mt < 4; ++mt)
          af[mt] = *reinterpret_cast<const s16x8*>(
              &ws[j][mt * 16 + l15][l4 * 8]);
#pragma unroll
        for (int nt = 0; nt < 4; ++nt)
          bf[nt] = *reinterpret_cast<const s16x8*>(
              &xs[wid + kh][nt * 16 + l15 + kw][l4 * 8]);
#pragma unroll
        for (int mt = 0; mt < 4; ++mt)
#pragma unroll
          for (int nt = 0; nt < 4; ++nt)
            acc[mt][nt] = __builtin_amdgcn_mfma_f32_16x16x32_bf16(
                af[mt], bf[nt], acc[mt][nt], 0, 0, 0);
      }
    }
    __syncthreads();
  }

  const int h = h0 + wid;
#pragma unroll
  for (int mt = 0; mt < 4; ++mt) {
#pragma unroll
    for (int r = 0; r < 4; ++r) {
      const int co = co0 + mt * 16 + l4 * 4 + r;
      const float osc = outscale[b * COUT + co];
      float* orow = out + (((size_t)b * COUT + co) * H + h) * W;
#pragma unroll
      for (int nt = 0; nt < 4; ++nt)
        orow[nt * 16 + l15] = acc[mt][nt][r] * osc;
    }
  }
}

// ---------------------------------------------------------------------------
extern "C" void kernel_launch(void* const* d_in, const int* in_sizes, int n_in,
                              void* d_out, int out_size, void* d_ws,
                              size_t ws_size, hipStream_t stream) {
  const float* x = (const float*)d_in[0];
  const float* style = (const float*)d_in[1];
  const float* weight = (const float*)d_in[2];
  const float* style_w = (const float*)d_in[3];
  const float* style_b = (const float*)d_in[4];
  float* out = (float*)d_out;

  // workspace layout (bytes):
  //   0        s        (32768)
  //   32768    s2       (32768)
  //   65536    wsq      (1048576)
  //   1114112  outscale (32768)
  //   1146880  wt       (4718592)   packed bf16 weights
  //   5865472  xp       (67108864)  packed bf16 x (s folded)
  char* wsb = (char*)d_ws;
  float* s = (float*)(wsb + 0);
  float* s2 = (float*)(wsb + 32768);
  float* wsq = (float*)(wsb + 65536);
  float* outscale = (float*)(wsb + 1114112);
  ushort* wt = (ushort*)(wsb + 1146880);
  ushort* xp = (ushort*)(wsb + 5865472);
  const size_t NEED = 72974336;

  style_mod_kernel<<<B, 512, 0, stream>>>(style, style_w, style_b, s, s2);
  wsq_kernel<<<(COUT * CIN + 255) / 256, 256, 0, stream>>>(weight, wsq);
  dcoef_kernel<<<B, 512, 0, stream>>>(s2, wsq, outscale);

  if (ws_size >= NEED) {
    pack_w_kernel<<<128, 256, 0, stream>>>(weight, wt);
    pack_x_kernel<<<dim3(64, 16, 16), 256, 0, stream>>>(x, s, xp);
    conv_mfma2_kernel<<<dim3(16, 8, 16), 256, 0, stream>>>(wt, xp, outscale,
                                                           out);
  } else {
    conv_mfma_kernel<<<dim3(16, 8, 16), 256, 0, stream>>>(x, weight, s,
                                                          outscale, out);
  }
}